// Round 2
// baseline (610.659 us; speedup 1.0000x reference)
//
#include <hip/hip_runtime.h>
#include <hip/hip_bf16.h>

// Problem constants: B=128, T=512, V=50000, E=100, U=128, K=32
#define B_  128
#define T_  512
#define V_  50000
#define VP  50016   // V padded to 32
#define E_  100
#define U_  128
#define K_  32
#define G4  512   // 4*U
#define KP  128   // padded K for MFMA GEMM
#define GRP 8     // lstm time-group size

typedef _Float16 h2_t __attribute__((ext_vector_type(2)));
typedef _Float16 f16x8 __attribute__((ext_vector_type(8)));
typedef __fp16   h2raw_t __attribute__((ext_vector_type(2)));
typedef short    bf16x8 __attribute__((ext_vector_type(8)));
typedef float    f32x4  __attribute__((ext_vector_type(4)));

__device__ __forceinline__ h2_t pk2(float a, float b) {
    h2raw_t r = __builtin_amdgcn_cvt_pkrtz(a, b);
    union { h2raw_t r; h2_t h; } u; u.r = r; return u.h;
}

#if __has_builtin(__builtin_amdgcn_rcpf)
__device__ __forceinline__ float rcp_f(float x) { return __builtin_amdgcn_rcpf(x); }
#else
__device__ __forceinline__ float rcp_f(float x) { return 1.f / x; }
#endif

__device__ __forceinline__ unsigned short bf16_bits(float v) {
    __hip_bfloat16 b = __float2bfloat16(v);
    union { __hip_bfloat16 b; unsigned short s; } u; u.b = b; return u.s;
}

// ---------------------------------------------------------------------------
// Kernel A0: pack Bb[n][k] (n-major, K padded to 128, bf16) from Wk_f|Wk_b.
// ---------------------------------------------------------------------------
__global__ __launch_bounds__(128) void pack_b_kernel(
    const float* __restrict__ Wk_f, const float* __restrict__ Wk_b,
    __hip_bfloat16* __restrict__ Bb)
{
    const int n = blockIdx.x;     // 0..1023
    const int k = threadIdx.x;    // 0..127
    float v = 0.f;
    if (k < E_) v = (n < 512) ? Wk_f[k * 512 + n] : Wk_b[k * 512 + (n - 512)];
    Bb[n * KP + k] = __float2bfloat16(v);
}

// ---------------------------------------------------------------------------
// Kernel A: proj[v][1024] = emb[v] @ [Wk_f | Wk_b] + [b_f | b_b], bf16.
// (unchanged this round)
// ---------------------------------------------------------------------------
__global__ __launch_bounds__(256, 2) void proj_mfma_kernel(
    const float* __restrict__ emb,
    const __hip_bfloat16* __restrict__ Bb,
    const float* __restrict__ b_f, const float* __restrict__ b_b,
    __hip_bfloat16* __restrict__ proj)
{
    const int r0   = blockIdx.x * 32;
    const int tid  = threadIdx.x;
    const int wv   = tid >> 6;
    const int lane = tid & 63;
    const int quad = lane >> 4;
    const int l16  = lane & 15;

    __shared__ __align__(16) float C_lds[32][268];          // 34.3 KB
    unsigned short* A_st = (unsigned short*)&C_lds[0][0];   // [32][136] alias

    for (int idx = tid; idx < 32 * 64; idx += 256) {
        int r = idx >> 6, kk = idx & 63;
        int vr = r0 + r; if (vr >= V_) vr = V_ - 1;   // clamp: no OOB
        unsigned int w = 0;
        if (kk < 50) {
            float2 v = *(const float2*)(emb + (long long)vr * E_ + 2 * kk);
            w = ((unsigned int)bf16_bits(v.y) << 16) | bf16_bits(v.x);
        }
        *(unsigned int*)&A_st[r * 136 + 2 * kk] = w;
    }
    __syncthreads();

    bf16x8 af[2][4];
    #pragma unroll
    for (int mt = 0; mt < 2; ++mt)
        #pragma unroll
        for (int kc = 0; kc < 4; ++kc)
            af[mt][kc] = *(const bf16x8*)&A_st[(mt * 16 + l16) * 136 +
                                               kc * 32 + quad * 8];
    __syncthreads();

    const unsigned short* Bu = (const unsigned short*)Bb;

    for (int ng = 0; ng < 4; ++ng) {
        const int n0 = ng * 256;

        bf16x8 bfr[4][4];
        #pragma unroll
        for (int nt = 0; nt < 4; ++nt)
            #pragma unroll
            for (int kc = 0; kc < 4; ++kc)
                bfr[nt][kc] = *(const bf16x8*)(Bu +
                    (n0 + wv * 64 + nt * 16 + l16) * KP + kc * 32 + quad * 8);

        f32x4 acc[2][4];
        #pragma unroll
        for (int mt = 0; mt < 2; ++mt)
            #pragma unroll
            for (int nt = 0; nt < 4; ++nt)
                acc[mt][nt] = (f32x4){0.f, 0.f, 0.f, 0.f};

        #pragma unroll
        for (int mt = 0; mt < 2; ++mt)
            #pragma unroll
            for (int nt = 0; nt < 4; ++nt)
                #pragma unroll
                for (int kc = 0; kc < 4; ++kc)
                    acc[mt][nt] = __builtin_amdgcn_mfma_f32_16x16x32_bf16(
                        af[mt][kc], bfr[nt][kc], acc[mt][nt], 0, 0, 0);

        #pragma unroll
        for (int mt = 0; mt < 2; ++mt)
            #pragma unroll
            for (int nt = 0; nt < 4; ++nt)
                #pragma unroll
                for (int v = 0; v < 4; ++v)
                    C_lds[mt * 16 + quad * 4 + v][wv * 64 + nt * 16 + l16] =
                        acc[mt][nt][v];
        __syncthreads();

        const float* bias = (n0 < 512) ? b_f : b_b;
        const int nbase = n0 & 511;
        for (int idx = tid; idx < 32 * 128; idx += 256) {
            int r = idx >> 7, cc = (idx & 127) * 2;
            float v0 = C_lds[r][cc]     + bias[nbase + cc];
            float v1 = C_lds[r][cc + 1] + bias[nbase + cc + 1];
            unsigned int w = ((unsigned int)bf16_bits(v1) << 16) | bf16_bits(v0);
            *(unsigned int*)(proj + (long long)(r0 + r) * 1024 + n0 + cc) = w;
        }
        __syncthreads();
    }
}

// ---------------------------------------------------------------------------
// Kernel B: LSTM recurrence, gate-local wave mapping.
//   This round:
//   (1) inner-step barrier = raw s_barrier + lgkmcnt(0) only — vmem
//       (xk prefetch loads, h_buf stores) stays in flight across steps
//       (T4: __syncthreads would drain vmcnt(0) every step).
//   (2) MFMA per gate split into two independent 2-deep pairs; only
//       element [0] is consumed, so z = pair0[0] + pair1[0] (chain 4L->2L).
//   (3) h_buf pack/shfl deferred to group end (off the serial path).
// ---------------------------------------------------------------------------
__device__ __forceinline__ float sigmoid_f(float x) {
    return rcp_f(1.f + __expf(-x));
}
__device__ __forceinline__ float tanh_f(float x) {
    return 1.f - 2.f * rcp_f(__expf(2.f * x) + 1.f);
}

__global__ __launch_bounds__(512, 2) void lstm_kernel(
    const __hip_bfloat16* __restrict__ proj,
    const int* __restrict__ tokens,
    const float* __restrict__ Wr_f, const float* __restrict__ Wr_b,
    __hip_bfloat16* __restrict__ h_buf)
{
    const int bid  = blockIdx.x;
    const int dir  = bid >> 7;
    const int b    = bid & 127;
    const int tid  = threadIdx.x;
    const int w    = tid >> 6;       // wave 0..7 -> units [16w, 16w+16)
    const int lane = tid & 63;
    const int quad = lane >> 4;
    const int l16  = lane & 15;
    const int unit = 16 * w + l16;   // this lane's unit

    const float* Wr = dir ? Wr_b : Wr_f;

    // B-frags: wb[g][kc]; element j = Wr[kc*32+quad*8+j][g*128 + unit]
    union uf16 { f16x8 v; h2_t p[4]; };
    f16x8 wb[4][4];
    #pragma unroll
    for (int gq = 0; gq < 4; ++gq) {
        const int col = gq * 128 + unit;
        #pragma unroll
        for (int kc = 0; kc < 4; ++kc) {
            const int k0 = kc * 32 + quad * 8;
            uf16 u;
            #pragma unroll
            for (int jj = 0; jj < 4; ++jj)
                u.p[jj] = pk2(Wr[(k0 + 2 * jj)     * G4 + col],
                              Wr[(k0 + 2 * jj + 1) * G4 + col]);
            wb[gq][kc] = u.v;
        }
    }

    // double-buffered h (f16), 2 x 256B; step s reads [s&1], writes [(s+1)&1]
    __shared__ __align__(16) _Float16 hpl[2][128];
    if (tid < 128) hpl[0][tid] = (_Float16)0.f;
    float c = 0.f;
    __syncthreads();   // once; vmcnt drain here is harmless

    const int tbase = b * T_;
    const long long rowbase = (long long)b * T_;
    // lane gather base: proj + tok*1024 + dir*512 + g*128 + unit
    const __hip_bfloat16* pr = proj + dir * 512 + unit;

    // token pipeline: cur (group g), nxt (g+1)
    int tok_cur[GRP], tok_nxt[GRP];
    #pragma unroll
    for (int d = 0; d < GRP; ++d) {
        int t0 = dir ? (T_ - 1 - d) : d;
        tok_cur[d] = tokens[tbase + t0];
        int t1 = dir ? (T_ - 1 - (GRP + d)) : (GRP + d);
        tok_nxt[d] = tokens[tbase + t1];
    }

    float xk_cur[GRP][4];
    #pragma unroll
    for (int d = 0; d < GRP; ++d)
        #pragma unroll
        for (int g = 0; g < 4; ++g)
            xk_cur[d][g] = __bfloat162float(
                pr[(long long)tok_cur[d] * 1024 + g * 128]);

    for (int g = 0; g < T_ / GRP; ++g) {
        // prefetch proj rows for group g+1 (tokens already resident)
        float xk_nxt[GRP][4];
        #pragma unroll
        for (int d = 0; d < GRP; ++d)
            #pragma unroll
            for (int gg = 0; gg < 4; ++gg) xk_nxt[d][gg] = 0.f;
        if (g + 1 < T_ / GRP) {
            #pragma unroll
            for (int d = 0; d < GRP; ++d)
                #pragma unroll
                for (int gg = 0; gg < 4; ++gg)
                    xk_nxt[d][gg] = __bfloat162float(
                        pr[(long long)tok_nxt[d] * 1024 + gg * 128]);
        }
        // token prefetch for group g+2
        int tok_n2[GRP];
        #pragma unroll
        for (int d = 0; d < GRP; ++d) tok_n2[d] = 0;
        if (g + 2 < T_ / GRP) {
            #pragma unroll
            for (int d = 0; d < GRP; ++d) {
                int s = (g + 2) * GRP + d;
                int t = dir ? (T_ - 1 - s) : s;
                tok_n2[d] = tokens[tbase + t];
            }
        }

        float hreg[GRP];

        #pragma unroll
        for (int d = 0; d < GRP; ++d) {
            // A-frag: broadcast h to all 16 rows (addr depends on quad only)
            f16x8 a[4];
            #pragma unroll
            for (int kc = 0; kc < 4; ++kc)
                a[kc] = *(const f16x8*)&hpl[d & 1][kc * 32 + quad * 8];

            // two independent 2-deep MFMA pairs per gate; only elem [0] used
            f32x4 t0[4], t1[4];
            #pragma unroll
            for (int gq = 0; gq < 4; ++gq) {
                t0[gq] = __builtin_amdgcn_mfma_f32_16x16x32_f16(
                    a[0], wb[gq][0], (f32x4){0.f, 0.f, 0.f, 0.f}, 0, 0, 0);
                t1[gq] = __builtin_amdgcn_mfma_f32_16x16x32_f16(
                    a[2], wb[gq][2], (f32x4){0.f, 0.f, 0.f, 0.f}, 0, 0, 0);
            }
            #pragma unroll
            for (int gq = 0; gq < 4; ++gq) {
                t0[gq] = __builtin_amdgcn_mfma_f32_16x16x32_f16(
                    a[1], wb[gq][1], t0[gq], 0, 0, 0);
                t1[gq] = __builtin_amdgcn_mfma_f32_16x16x32_f16(
                    a[3], wb[gq][3], t1[gq], 0, 0, 0);
            }

            float zi = (t0[0][0] + t1[0][0]) + xk_cur[d][0];
            float zf = (t0[1][0] + t1[1][0]) + xk_cur[d][1];
            float zg = (t0[2][0] + t1[2][0]) + xk_cur[d][2];
            float zo = (t0[3][0] + t1[3][0]) + xk_cur[d][3];
            c = sigmoid_f(zf) * c + sigmoid_f(zi) * tanh_f(zg);
            float h = sigmoid_f(zo) * tanh_f(c);
            hreg[d] = h;

            // publish h for next step (quad 0 writes its 16 units)
            if (quad == 0) hpl[(d + 1) & 1][unit] = (_Float16)h;

            // LDS-only barrier: drain lgkm, leave vmem in flight (T4)
            asm volatile("s_waitcnt lgkmcnt(0)" ::: "memory");
            __builtin_amdgcn_s_barrier();
        }

        // group-end: pack h pairs to bf16 and store (off the serial path)
        unsigned int hp[GRP];
        #pragma unroll
        for (int d = 0; d < GRP; ++d) {
            float hn = __shfl_down(hreg[d], 1, 64);
            hp[d] = ((unsigned int)bf16_bits(hn) << 16) | bf16_bits(hreg[d]);
        }
        if (quad == 0 && !(l16 & 1)) {
            #pragma unroll
            for (int d = 0; d < GRP; ++d) {
                int s = g * GRP + d;
                int t = dir ? (T_ - 1 - s) : s;
                *(unsigned int*)(h_buf + (rowbase + t) * 256 + dir * U_ + unit) =
                    hp[d];
            }
        }

        #pragma unroll
        for (int d = 0; d < GRP; ++d) {
            #pragma unroll
            for (int gg = 0; gg < 4; ++gg) xk_cur[d][gg] = xk_nxt[d][gg];
            tok_nxt[d] = tok_n2[d];
        }
    }
}

// ---------------------------------------------------------------------------
// Kernel C: em = h_buf(65536x256 bf16) @ ck(256x32) + cb  -> f32 (65536x32).
// ---------------------------------------------------------------------------
__global__ __launch_bounds__(256) void em_kernel(
    const __hip_bfloat16* __restrict__ h_buf,
    const float* __restrict__ ck, const float* __restrict__ cb,
    float* __restrict__ em)
{
    const int tid  = threadIdx.x;
    const int part = tid >> 5;
    const int k    = tid & 31;

    float ckr[32];
    #pragma unroll
    for (int i = 0; i < 32; ++i)
        ckr[i] = ck[(part * 32 + i) * K_ + k];
    const float cbk = cb[k];

    __shared__ float h_l[8][256];
    __shared__ float part_l[8][8][K_];

    const int r0 = blockIdx.x * 64;

    for (int round = 0; round < 8; ++round) {
        const int rbase = r0 + round * 8;
        #pragma unroll
        for (int j = 0; j < 8; ++j)
            h_l[j][tid] = __bfloat162float(h_buf[(long long)(rbase + j) * 256 + tid]);
        __syncthreads();

        #pragma unroll
        for (int j = 0; j < 8; ++j) {
            float pp = 0.f;
            #pragma unroll
            for (int i = 0; i < 32; ++i)
                pp = fmaf(h_l[j][part * 32 + i], ckr[i], pp);
            part_l[j][part][k] = pp;
        }
        __syncthreads();

        {
            int j2 = tid >> 5;
            float e = cbk;
            #pragma unroll
            for (int pq = 0; pq < 8; ++pq) e += part_l[j2][pq][k];
            em[(long long)(rbase + j2) * K_ + k] = e;
        }
        __syncthreads();
    }
}

// ---------------------------------------------------------------------------
// Kernel D: CRF logZ — linear-space chain.
// ---------------------------------------------------------------------------
#define PF_ 8
__global__ __launch_bounds__(64) void crf_kernel(
    const float* __restrict__ em,
    const float* __restrict__ trans,
    float* __restrict__ out)
{
    const int b    = blockIdx.x;
    const int lane = threadIdx.x;
    const int k    = lane & 31;
    const int half = lane >> 5;

    float etr[16];
    #pragma unroll
    for (int i = 0; i < 16; ++i)
        etr[i] = __expf(trans[(half * 16 + i) * K_ + k]);

    const float* em_b = em + (long long)b * T_ * K_;

    float ep[PF_];
    #pragma unroll
    for (int d = 0; d < PF_; ++d)
        ep[d] = em_b[d * K_ + k];

    float w = 0.f;    // linear-space alpha, scaled
    float L = 0.f;    // accumulated log-scale
    for (int tb = 0; tb < T_; tb += PF_) {
        float en[PF_];
        if (tb + PF_ < T_) {
            #pragma unroll
            for (int d = 0; d < PF_; ++d)
                en[d] = em_b[(tb + PF_ + d) * K_ + k];
        } else {
            #pragma unroll
            for (int d = 0; d < PF_; ++d) en[d] = 0.f;
        }

        float eem[PF_];
        #pragma unroll
        for (int d = 0; d < PF_; ++d) eem[d] = __expf(ep[d]);

        #pragma unroll
        for (int d = 0; d < PF_; ++d) {
            if (tb + d == 0) {
                w = eem[d];
            } else {
                float acc = 0.f;
                #pragma unroll
                for (int i = 0; i < 16; ++i) {
                    float wv = __shfl(w, half * 16 + i, 64);
                    acc = fmaf(wv, etr[i], acc);
                }
                acc += __shfl_xor(acc, 32, 64);
                w = acc * eem[d];
            }
        }

        {
            float w0 = __shfl(w, 0, 64);
            w *= rcp_f(w0);
            L += __logf(w0);
        }

        #pragma unroll
        for (int d = 0; d < PF_; ++d) ep[d] = en[d];
    }

    float s = w;
    #pragma unroll
    for (int d = 1; d < 32; d <<= 1)
        s += __shfl_xor(s, d, 64);
    if (lane == 0) out[b] = L + __logf(s);
}

// ---------------------------------------------------------------------------
extern "C" void kernel_launch(void* const* d_in, const int* in_sizes, int n_in,
                              void* d_out, int out_size, void* d_ws, size_t ws_size,
                              hipStream_t stream)
{
    const int*   tokens = (const int*)  d_in[0];
    const float* emb    = (const float*)d_in[1];
    const float* Wk_f   = (const float*)d_in[2];
    const float* Wr_f   = (const float*)d_in[3];
    const float* b_f    = (const float*)d_in[4];
    const float* Wk_b   = (const float*)d_in[5];
    const float* Wr_b   = (const float*)d_in[6];
    const float* b_b    = (const float*)d_in[7];
    const float* ck     = (const float*)d_in[8];
    const float* cb     = (const float*)d_in[9];
    const float* trans  = (const float*)d_in[10];
    float* out = (float*)d_out;

    // ws layout: proj (VP*1024 bf16 = 102.4MB) | h_buf (33.6MB) |
    //            em (8.4MB f32) | Bb (256KB bf16).  Total ~144.7MB.
    const long long ROWS = (long long)B_ * T_;     // 65536
    __hip_bfloat16* proj  = (__hip_bfloat16*)d_ws;
    __hip_bfloat16* h_buf = proj + (long long)VP * 1024;
    float* em = (float*)(h_buf + ROWS * 256);
    __hip_bfloat16* Bb = (__hip_bfloat16*)(em + ROWS * K_);

    hipLaunchKernelGGL(pack_b_kernel, dim3(1024), dim3(128), 0, stream,
                       Wk_f, Wk_b, Bb);
    hipLaunchKernelGGL(proj_mfma_kernel, dim3(VP / 32), dim3(256), 0, stream,
                       emb, Bb, b_f, b_b, proj);
    hipLaunchKernelGGL(lstm_kernel, dim3(256), dim3(512), 0, stream,
                       proj, tokens, Wr_f, Wr_b, h_buf);
    hipLaunchKernelGGL(em_kernel, dim3((int)(ROWS / 64)), dim3(256), 0, stream,
                       h_buf, ck, cb, em);
    hipLaunchKernelGGL(crf_kernel, dim3(B_), dim3(64), 0, stream,
                       em, trans, out);
}

// Round 3
// 597.429 us; speedup vs baseline: 1.0221x; 1.0221x over previous
//
#include <hip/hip_runtime.h>
#include <hip/hip_bf16.h>

// Problem constants: B=128, T=512, V=50000, E=100, U=128, K=32
#define B_  128
#define T_  512
#define V_  50000
#define VP  50016   // V padded to 32
#define E_  100
#define U_  128
#define K_  32
#define G4  512   // 4*U
#define KP  128   // padded K for MFMA GEMM
#define GRP 8     // lstm time-group size

typedef _Float16 h2_t __attribute__((ext_vector_type(2)));
typedef _Float16 f16x8 __attribute__((ext_vector_type(8)));
typedef __fp16   h2raw_t __attribute__((ext_vector_type(2)));
typedef short    bf16x8 __attribute__((ext_vector_type(8)));
typedef float    f32x4  __attribute__((ext_vector_type(4)));

__device__ __forceinline__ h2_t pk2(float a, float b) {
    h2raw_t r = __builtin_amdgcn_cvt_pkrtz(a, b);
    union { h2raw_t r; h2_t h; } u; u.r = r; return u.h;
}
__device__ __forceinline__ int h2_as_int(h2_t v) { union { h2_t h; int i; } u; u.h = v; return u.i; }

#if __has_builtin(__builtin_amdgcn_rcpf)
__device__ __forceinline__ float rcp_f(float x) { return __builtin_amdgcn_rcpf(x); }
#else
__device__ __forceinline__ float rcp_f(float x) { return 1.f / x; }
#endif

__device__ __forceinline__ unsigned short bf16_bits(float v) {
    __hip_bfloat16 b = __float2bfloat16(v);
    union { __hip_bfloat16 b; unsigned short s; } u; u.b = b; return u.s;
}

// ---------------------------------------------------------------------------
// Kernel A0: pack Bb[n][k] (n-major, K padded to 128, bf16) from Wk_f|Wk_b.
// ---------------------------------------------------------------------------
__global__ __launch_bounds__(128) void pack_b_kernel(
    const float* __restrict__ Wk_f, const float* __restrict__ Wk_b,
    __hip_bfloat16* __restrict__ Bb)
{
    const int n = blockIdx.x;     // 0..1023
    const int k = threadIdx.x;    // 0..127
    float v = 0.f;
    if (k < E_) v = (n < 512) ? Wk_f[k * 512 + n] : Wk_b[k * 512 + (n - 512)];
    Bb[n * KP + k] = __float2bfloat16(v);
}

// ---------------------------------------------------------------------------
// Kernel A: proj[v][1024] = emb[v] @ [Wk_f | Wk_b] + [b_f | b_b], bf16.
// (unchanged this round)
// ---------------------------------------------------------------------------
__global__ __launch_bounds__(256, 2) void proj_mfma_kernel(
    const float* __restrict__ emb,
    const __hip_bfloat16* __restrict__ Bb,
    const float* __restrict__ b_f, const float* __restrict__ b_b,
    __hip_bfloat16* __restrict__ proj)
{
    const int r0   = blockIdx.x * 32;
    const int tid  = threadIdx.x;
    const int wv   = tid >> 6;
    const int lane = tid & 63;
    const int quad = lane >> 4;
    const int l16  = lane & 15;

    __shared__ __align__(16) float C_lds[32][268];          // 34.3 KB
    unsigned short* A_st = (unsigned short*)&C_lds[0][0];   // [32][136] alias

    for (int idx = tid; idx < 32 * 64; idx += 256) {
        int r = idx >> 6, kk = idx & 63;
        int vr = r0 + r; if (vr >= V_) vr = V_ - 1;   // clamp: no OOB
        unsigned int w = 0;
        if (kk < 50) {
            float2 v = *(const float2*)(emb + (long long)vr * E_ + 2 * kk);
            w = ((unsigned int)bf16_bits(v.y) << 16) | bf16_bits(v.x);
        }
        *(unsigned int*)&A_st[r * 136 + 2 * kk] = w;
    }
    __syncthreads();

    bf16x8 af[2][4];
    #pragma unroll
    for (int mt = 0; mt < 2; ++mt)
        #pragma unroll
        for (int kc = 0; kc < 4; ++kc)
            af[mt][kc] = *(const bf16x8*)&A_st[(mt * 16 + l16) * 136 +
                                               kc * 32 + quad * 8];
    __syncthreads();

    const unsigned short* Bu = (const unsigned short*)Bb;

    for (int ng = 0; ng < 4; ++ng) {
        const int n0 = ng * 256;

        bf16x8 bfr[4][4];
        #pragma unroll
        for (int nt = 0; nt < 4; ++nt)
            #pragma unroll
            for (int kc = 0; kc < 4; ++kc)
                bfr[nt][kc] = *(const bf16x8*)(Bu +
                    (n0 + wv * 64 + nt * 16 + l16) * KP + kc * 32 + quad * 8);

        f32x4 acc[2][4];
        #pragma unroll
        for (int mt = 0; mt < 2; ++mt)
            #pragma unroll
            for (int nt = 0; nt < 4; ++nt)
                acc[mt][nt] = (f32x4){0.f, 0.f, 0.f, 0.f};

        #pragma unroll
        for (int mt = 0; mt < 2; ++mt)
            #pragma unroll
            for (int nt = 0; nt < 4; ++nt)
                #pragma unroll
                for (int kc = 0; kc < 4; ++kc)
                    acc[mt][nt] = __builtin_amdgcn_mfma_f32_16x16x32_bf16(
                        af[mt][kc], bfr[nt][kc], acc[mt][nt], 0, 0, 0);

        #pragma unroll
        for (int mt = 0; mt < 2; ++mt)
            #pragma unroll
            for (int nt = 0; nt < 4; ++nt)
                #pragma unroll
                for (int v = 0; v < 4; ++v)
                    C_lds[mt * 16 + quad * 4 + v][wv * 64 + nt * 16 + l16] =
                        acc[mt][nt][v];
        __syncthreads();

        const float* bias = (n0 < 512) ? b_f : b_b;
        const int nbase = n0 & 511;
        for (int idx = tid; idx < 32 * 128; idx += 256) {
            int r = idx >> 7, cc = (idx & 127) * 2;
            float v0 = C_lds[r][cc]     + bias[nbase + cc];
            float v1 = C_lds[r][cc + 1] + bias[nbase + cc + 1];
            unsigned int w = ((unsigned int)bf16_bits(v1) << 16) | bf16_bits(v0);
            *(unsigned int*)(proj + (long long)(r0 + r) * 1024 + n0 + cc) = w;
        }
        __syncthreads();
    }
}

// ---------------------------------------------------------------------------
// Kernel B: LSTM recurrence, gate-local wave mapping (R1 structure).
//   Single change this round: __launch_bounds__(512, 1) — the old (512,2)
//   capped the allocator at 128 VGPRs while live state (wb=64, xk banks=64,
//   token pipeline, hpack) needs ~160. Grid=256 on 256 CUs means only one
//   block/CU ever resides, so the ",2" bought nothing and forced the
//   compiler to sink/remat the xk prefetch gathers onto the serial path.
// ---------------------------------------------------------------------------
__device__ __forceinline__ float sigmoid_f(float x) {
    return rcp_f(1.f + __expf(-x));
}
__device__ __forceinline__ float tanh_f(float x) {
    return 1.f - 2.f * rcp_f(__expf(2.f * x) + 1.f);
}

__global__ __launch_bounds__(512, 1) void lstm_kernel(
    const __hip_bfloat16* __restrict__ proj,
    const int* __restrict__ tokens,
    const float* __restrict__ Wr_f, const float* __restrict__ Wr_b,
    __hip_bfloat16* __restrict__ h_buf)
{
    const int bid  = blockIdx.x;
    const int dir  = bid >> 7;
    const int b    = bid & 127;
    const int tid  = threadIdx.x;
    const int w    = tid >> 6;       // wave 0..7 -> units [16w, 16w+16)
    const int lane = tid & 63;
    const int quad = lane >> 4;
    const int l16  = lane & 15;
    const int unit = 16 * w + l16;   // this lane's unit

    const float* Wr = dir ? Wr_b : Wr_f;

    // B-frags: wb[g][kc]; element j = Wr[kc*32+quad*8+j][g*128 + unit]
    union uf16 { f16x8 v; h2_t p[4]; };
    f16x8 wb[4][4];
    #pragma unroll
    for (int gq = 0; gq < 4; ++gq) {
        const int col = gq * 128 + unit;
        #pragma unroll
        for (int kc = 0; kc < 4; ++kc) {
            const int k0 = kc * 32 + quad * 8;
            uf16 u;
            #pragma unroll
            for (int jj = 0; jj < 4; ++jj)
                u.p[jj] = pk2(Wr[(k0 + 2 * jj)     * G4 + col],
                              Wr[(k0 + 2 * jj + 1) * G4 + col]);
            wb[gq][kc] = u.v;
        }
    }

    // double-buffered h (f16), 2 x 256B; step s reads [s&1], writes [(s+1)&1]
    __shared__ __align__(16) _Float16 hpl[2][128];
    if (tid < 128) hpl[0][tid] = (_Float16)0.f;
    float c = 0.f;
    __syncthreads();

    const int tbase = b * T_;
    const long long rowbase = (long long)b * T_;
    // lane gather base: proj + tok*1024 + dir*512 + g*128 + unit
    const __hip_bfloat16* pr = proj + dir * 512 + unit;

    // token pipeline: cur (group g), nxt (g+1)
    int tok_cur[GRP], tok_nxt[GRP];
    #pragma unroll
    for (int d = 0; d < GRP; ++d) {
        int t0 = dir ? (T_ - 1 - d) : d;
        tok_cur[d] = tokens[tbase + t0];
        int t1 = dir ? (T_ - 1 - (GRP + d)) : (GRP + d);
        tok_nxt[d] = tokens[tbase + t1];
    }

    float xk_cur[GRP][4];
    #pragma unroll
    for (int d = 0; d < GRP; ++d)
        #pragma unroll
        for (int g = 0; g < 4; ++g)
            xk_cur[d][g] = __bfloat162float(
                pr[(long long)tok_cur[d] * 1024 + g * 128]);

    unsigned int hpack[GRP];
    #pragma unroll
    for (int d = 0; d < GRP; ++d) hpack[d] = 0;

    for (int g = 0; g < T_ / GRP; ++g) {
        // prefetch proj rows for group g+1 (tokens already resident)
        float xk_nxt[GRP][4];
        #pragma unroll
        for (int d = 0; d < GRP; ++d)
            #pragma unroll
            for (int gg = 0; gg < 4; ++gg) xk_nxt[d][gg] = 0.f;
        if (g + 1 < T_ / GRP) {
            #pragma unroll
            for (int d = 0; d < GRP; ++d)
                #pragma unroll
                for (int gg = 0; gg < 4; ++gg)
                    xk_nxt[d][gg] = __bfloat162float(
                        pr[(long long)tok_nxt[d] * 1024 + gg * 128]);
        }
        // token prefetch for group g+2
        int tok_n2[GRP];
        #pragma unroll
        for (int d = 0; d < GRP; ++d) tok_n2[d] = 0;
        if (g + 2 < T_ / GRP) {
            #pragma unroll
            for (int d = 0; d < GRP; ++d) {
                int s = (g + 2) * GRP + d;
                int t = dir ? (T_ - 1 - s) : s;
                tok_n2[d] = tokens[tbase + t];
            }
        }

        #pragma unroll
        for (int d = 0; d < GRP; ++d) {
            // A-frag: broadcast h to all 16 rows (addr depends on quad only)
            f16x8 a[4];
            #pragma unroll
            for (int kc = 0; kc < 4; ++kc)
                a[kc] = *(const f16x8*)&hpl[d & 1][kc * 32 + quad * 8];

            f32x4 acc[4];
            #pragma unroll
            for (int gq = 0; gq < 4; ++gq)
                acc[gq] = (f32x4){0.f, 0.f, 0.f, 0.f};
            #pragma unroll
            for (int gq = 0; gq < 4; ++gq)
                #pragma unroll
                for (int kc = 0; kc < 4; ++kc)
                    acc[gq] = __builtin_amdgcn_mfma_f32_16x16x32_f16(
                        a[kc], wb[gq][kc], acc[gq], 0, 0, 0);

            // every lane holds z for its unit in acc[g][0] (rows identical)
            float zi = acc[0][0] + xk_cur[d][0];
            float zf = acc[1][0] + xk_cur[d][1];
            float zg = acc[2][0] + xk_cur[d][2];
            float zo = acc[3][0] + xk_cur[d][3];
            c = sigmoid_f(zf) * c + sigmoid_f(zi) * tanh_f(zg);
            float h = sigmoid_f(zo) * tanh_f(c);

            // publish h for next step (quad 0 writes its 16 units)
            if (quad == 0) hpl[(d + 1) & 1][unit] = (_Float16)h;

            // bf16 pair for h_buf (stored at group end, off critical path)
            float hn = __shfl_down(h, 1, 64);
            if (quad == 0 && !(l16 & 1))
                hpack[d] = ((unsigned int)bf16_bits(hn) << 16) | bf16_bits(h);

            __syncthreads();
        }

        // clustered h stores
        if (quad == 0 && !(l16 & 1)) {
            #pragma unroll
            for (int d = 0; d < GRP; ++d) {
                int s = g * GRP + d;
                int t = dir ? (T_ - 1 - s) : s;
                *(unsigned int*)(h_buf + (rowbase + t) * 256 + dir * U_ + unit) =
                    hpack[d];
            }
        }

        #pragma unroll
        for (int d = 0; d < GRP; ++d) {
            #pragma unroll
            for (int gg = 0; gg < 4; ++gg) xk_cur[d][gg] = xk_nxt[d][gg];
            tok_nxt[d] = tok_n2[d];
        }
    }
}

// ---------------------------------------------------------------------------
// Kernel C: em = h_buf(65536x256 bf16) @ ck(256x32) + cb  -> f32 (65536x32).
// ---------------------------------------------------------------------------
__global__ __launch_bounds__(256) void em_kernel(
    const __hip_bfloat16* __restrict__ h_buf,
    const float* __restrict__ ck, const float* __restrict__ cb,
    float* __restrict__ em)
{
    const int tid  = threadIdx.x;
    const int part = tid >> 5;
    const int k    = tid & 31;

    float ckr[32];
    #pragma unroll
    for (int i = 0; i < 32; ++i)
        ckr[i] = ck[(part * 32 + i) * K_ + k];
    const float cbk = cb[k];

    __shared__ float h_l[8][256];
    __shared__ float part_l[8][8][K_];

    const int r0 = blockIdx.x * 64;

    for (int round = 0; round < 8; ++round) {
        const int rbase = r0 + round * 8;
        #pragma unroll
        for (int j = 0; j < 8; ++j)
            h_l[j][tid] = __bfloat162float(h_buf[(long long)(rbase + j) * 256 + tid]);
        __syncthreads();

        #pragma unroll
        for (int j = 0; j < 8; ++j) {
            float pp = 0.f;
            #pragma unroll
            for (int i = 0; i < 32; ++i)
                pp = fmaf(h_l[j][part * 32 + i], ckr[i], pp);
            part_l[j][part][k] = pp;
        }
        __syncthreads();

        {
            int j2 = tid >> 5;
            float e = cbk;
            #pragma unroll
            for (int pq = 0; pq < 8; ++pq) e += part_l[j2][pq][k];
            em[(long long)(rbase + j2) * K_ + k] = e;
        }
        __syncthreads();
    }
}

// ---------------------------------------------------------------------------
// Kernel D: CRF logZ — linear-space chain.
// ---------------------------------------------------------------------------
#define PF_ 8
__global__ __launch_bounds__(64) void crf_kernel(
    const float* __restrict__ em,
    const float* __restrict__ trans,
    float* __restrict__ out)
{
    const int b    = blockIdx.x;
    const int lane = threadIdx.x;
    const int k    = lane & 31;
    const int half = lane >> 5;

    float etr[16];
    #pragma unroll
    for (int i = 0; i < 16; ++i)
        etr[i] = __expf(trans[(half * 16 + i) * K_ + k]);

    const float* em_b = em + (long long)b * T_ * K_;

    float ep[PF_];
    #pragma unroll
    for (int d = 0; d < PF_; ++d)
        ep[d] = em_b[d * K_ + k];

    float w = 0.f;    // linear-space alpha, scaled
    float L = 0.f;    // accumulated log-scale
    for (int tb = 0; tb < T_; tb += PF_) {
        float en[PF_];
        if (tb + PF_ < T_) {
            #pragma unroll
            for (int d = 0; d < PF_; ++d)
                en[d] = em_b[(tb + PF_ + d) * K_ + k];
        } else {
            #pragma unroll
            for (int d = 0; d < PF_; ++d) en[d] = 0.f;
        }

        float eem[PF_];
        #pragma unroll
        for (int d = 0; d < PF_; ++d) eem[d] = __expf(ep[d]);

        #pragma unroll
        for (int d = 0; d < PF_; ++d) {
            if (tb + d == 0) {
                w = eem[d];
            } else {
                float acc = 0.f;
                #pragma unroll
                for (int i = 0; i < 16; ++i) {
                    float wv = __shfl(w, half * 16 + i, 64);
                    acc = fmaf(wv, etr[i], acc);
                }
                acc += __shfl_xor(acc, 32, 64);
                w = acc * eem[d];
            }
        }

        {
            float w0 = __shfl(w, 0, 64);
            w *= rcp_f(w0);
            L += __logf(w0);
        }

        #pragma unroll
        for (int d = 0; d < PF_; ++d) ep[d] = en[d];
    }

    float s = w;
    #pragma unroll
    for (int d = 1; d < 32; d <<= 1)
        s += __shfl_xor(s, d, 64);
    if (lane == 0) out[b] = L + __logf(s);
}

// ---------------------------------------------------------------------------
extern "C" void kernel_launch(void* const* d_in, const int* in_sizes, int n_in,
                              void* d_out, int out_size, void* d_ws, size_t ws_size,
                              hipStream_t stream)
{
    const int*   tokens = (const int*)  d_in[0];
    const float* emb    = (const float*)d_in[1];
    const float* Wk_f   = (const float*)d_in[2];
    const float* Wr_f   = (const float*)d_in[3];
    const float* b_f    = (const float*)d_in[4];
    const float* Wk_b   = (const float*)d_in[5];
    const float* Wr_b   = (const float*)d_in[6];
    const float* b_b    = (const float*)d_in[7];
    const float* ck     = (const float*)d_in[8];
    const float* cb     = (const float*)d_in[9];
    const float* trans  = (const float*)d_in[10];
    float* out = (float*)d_out;

    // ws layout: proj (VP*1024 bf16 = 102.4MB) | h_buf (33.6MB) |
    //            em (8.4MB f32) | Bb (256KB bf16).  Total ~144.7MB.
    const long long ROWS = (long long)B_ * T_;     // 65536
    __hip_bfloat16* proj  = (__hip_bfloat16*)d_ws;
    __hip_bfloat16* h_buf = proj + (long long)VP * 1024;
    float* em = (float*)(h_buf + ROWS * 256);
    __hip_bfloat16* Bb = (__hip_bfloat16*)(em + ROWS * K_);

    hipLaunchKernelGGL(pack_b_kernel, dim3(1024), dim3(128), 0, stream,
                       Wk_f, Wk_b, Bb);
    hipLaunchKernelGGL(proj_mfma_kernel, dim3(VP / 32), dim3(256), 0, stream,
                       emb, Bb, b_f, b_b, proj);
    hipLaunchKernelGGL(lstm_kernel, dim3(256), dim3(512), 0, stream,
                       proj, tokens, Wr_f, Wr_b, h_buf);
    hipLaunchKernelGGL(em_kernel, dim3((int)(ROWS / 64)), dim3(256), 0, stream,
                       h_buf, ck, cb, em);
    hipLaunchKernelGGL(crf_kernel, dim3(B_), dim3(64), 0, stream,
                       em, trans, out);
}

// Round 4
// 575.722 us; speedup vs baseline: 1.0607x; 1.0377x over previous
//
#include <hip/hip_runtime.h>
#include <hip/hip_bf16.h>

// Problem constants: B=128, T=512, V=50000, E=100, U=128, K=32
#define B_  128
#define T_  512
#define V_  50000
#define VP  50016   // V padded to 32
#define E_  100
#define U_  128
#define K_  32
#define G4  512   // 4*U
#define KP  128   // padded K for MFMA GEMM
#define GRP 8     // lstm time-group size

typedef _Float16 h2_t __attribute__((ext_vector_type(2)));
typedef _Float16 f16x8 __attribute__((ext_vector_type(8)));
typedef __fp16   h2raw_t __attribute__((ext_vector_type(2)));
typedef short    bf16x8 __attribute__((ext_vector_type(8)));
typedef float    f32x4  __attribute__((ext_vector_type(4)));
typedef unsigned short u16x4 __attribute__((ext_vector_type(4)));

__device__ __forceinline__ h2_t pk2(float a, float b) {
    h2raw_t r = __builtin_amdgcn_cvt_pkrtz(a, b);
    union { h2raw_t r; h2_t h; } u; u.r = r; return u.h;
}

#if __has_builtin(__builtin_amdgcn_rcpf)
__device__ __forceinline__ float rcp_f(float x) { return __builtin_amdgcn_rcpf(x); }
#else
__device__ __forceinline__ float rcp_f(float x) { return 1.f / x; }
#endif

__device__ __forceinline__ unsigned short bf16_bits(float v) {
    __hip_bfloat16 b = __float2bfloat16(v);
    union { __hip_bfloat16 b; unsigned short s; } u; u.b = b; return u.s;
}
__device__ __forceinline__ float bf2f(unsigned short u) {
    union { unsigned int i; float f; } x; x.i = ((unsigned int)u) << 16; return x.f;
}

// ---------------------------------------------------------------------------
// Kernel A0: pack Bb[n][k] (n-major, K padded to 128, bf16) from Wk_f|Wk_b.
// ---------------------------------------------------------------------------
__global__ __launch_bounds__(128) void pack_b_kernel(
    const float* __restrict__ Wk_f, const float* __restrict__ Wk_b,
    __hip_bfloat16* __restrict__ Bb)
{
    const int n = blockIdx.x;     // 0..1023
    const int k = threadIdx.x;    // 0..127
    float v = 0.f;
    if (k < E_) v = (n < 512) ? Wk_f[k * 512 + n] : Wk_b[k * 512 + (n - 512)];
    Bb[n * KP + k] = __float2bfloat16(v);
}

// ---------------------------------------------------------------------------
// Kernel A: proj[v][1024] = emb[v] @ [Wk_f | Wk_b] + [b_f | b_b], bf16.
// (unchanged this round)
// ---------------------------------------------------------------------------
__global__ __launch_bounds__(256, 2) void proj_mfma_kernel(
    const float* __restrict__ emb,
    const __hip_bfloat16* __restrict__ Bb,
    const float* __restrict__ b_f, const float* __restrict__ b_b,
    __hip_bfloat16* __restrict__ proj)
{
    const int r0   = blockIdx.x * 32;
    const int tid  = threadIdx.x;
    const int wv   = tid >> 6;
    const int lane = tid & 63;
    const int quad = lane >> 4;
    const int l16  = lane & 15;

    __shared__ __align__(16) float C_lds[32][268];          // 34.3 KB
    unsigned short* A_st = (unsigned short*)&C_lds[0][0];   // [32][136] alias

    for (int idx = tid; idx < 32 * 64; idx += 256) {
        int r = idx >> 6, kk = idx & 63;
        int vr = r0 + r; if (vr >= V_) vr = V_ - 1;   // clamp: no OOB
        unsigned int w = 0;
        if (kk < 50) {
            float2 v = *(const float2*)(emb + (long long)vr * E_ + 2 * kk);
            w = ((unsigned int)bf16_bits(v.y) << 16) | bf16_bits(v.x);
        }
        *(unsigned int*)&A_st[r * 136 + 2 * kk] = w;
    }
    __syncthreads();

    bf16x8 af[2][4];
    #pragma unroll
    for (int mt = 0; mt < 2; ++mt)
        #pragma unroll
        for (int kc = 0; kc < 4; ++kc)
            af[mt][kc] = *(const bf16x8*)&A_st[(mt * 16 + l16) * 136 +
                                               kc * 32 + quad * 8];
    __syncthreads();

    const unsigned short* Bu = (const unsigned short*)Bb;

    for (int ng = 0; ng < 4; ++ng) {
        const int n0 = ng * 256;

        bf16x8 bfr[4][4];
        #pragma unroll
        for (int nt = 0; nt < 4; ++nt)
            #pragma unroll
            for (int kc = 0; kc < 4; ++kc)
                bfr[nt][kc] = *(const bf16x8*)(Bu +
                    (n0 + wv * 64 + nt * 16 + l16) * KP + kc * 32 + quad * 8);

        f32x4 acc[2][4];
        #pragma unroll
        for (int mt = 0; mt < 2; ++mt)
            #pragma unroll
            for (int nt = 0; nt < 4; ++nt)
                acc[mt][nt] = (f32x4){0.f, 0.f, 0.f, 0.f};

        #pragma unroll
        for (int mt = 0; mt < 2; ++mt)
            #pragma unroll
            for (int nt = 0; nt < 4; ++nt)
                #pragma unroll
                for (int kc = 0; kc < 4; ++kc)
                    acc[mt][nt] = __builtin_amdgcn_mfma_f32_16x16x32_bf16(
                        af[mt][kc], bfr[nt][kc], acc[mt][nt], 0, 0, 0);

        #pragma unroll
        for (int mt = 0; mt < 2; ++mt)
            #pragma unroll
            for (int nt = 0; nt < 4; ++nt)
                #pragma unroll
                for (int v = 0; v < 4; ++v)
                    C_lds[mt * 16 + quad * 4 + v][wv * 64 + nt * 16 + l16] =
                        acc[mt][nt][v];
        __syncthreads();

        const float* bias = (n0 < 512) ? b_f : b_b;
        const int nbase = n0 & 511;
        for (int idx = tid; idx < 32 * 128; idx += 256) {
            int r = idx >> 7, cc = (idx & 127) * 2;
            float v0 = C_lds[r][cc]     + bias[nbase + cc];
            float v1 = C_lds[r][cc + 1] + bias[nbase + cc + 1];
            unsigned int w = ((unsigned int)bf16_bits(v1) << 16) | bf16_bits(v0);
            *(unsigned int*)(proj + (long long)(r0 + r) * 1024 + n0 + cc) = w;
        }
        __syncthreads();
    }
}

// ---------------------------------------------------------------------------
// Kernel B: LSTM recurrence, gate-local wave mapping.
//   This round (single mechanism: vmem off the serial step path):
//   (1) xk staged via LDS (T14 async-STAGE): all 512 threads do ONE
//       coalesced 2B load per step-row, issued one GROUP ahead, held in
//       8 regs, ds_write'd to xkl[] at group end. Un-sinkable by regalloc;
//       per-step xk read is an 8B LDS broadcast.
//   (2) steps 0..6 use lgkm-only barriers (s_waitcnt lgkmcnt(0) +
//       s_barrier + asm fence) so the in-flight group loads are NOT
//       drained per step (T4). The group-end ds_write's data dependence
//       inserts the single vmcnt wait, ~a full group after issue.
//   (3) h_buf shfl/pack deferred to group end (hreg[8]).
// ---------------------------------------------------------------------------
__device__ __forceinline__ float sigmoid_f(float x) {
    return rcp_f(1.f + __expf(-x));
}
__device__ __forceinline__ float tanh_f(float x) {
    return 1.f - 2.f * rcp_f(__expf(2.f * x) + 1.f);
}

__global__ __launch_bounds__(512, 1) void lstm_kernel(
    const __hip_bfloat16* __restrict__ proj,
    const int* __restrict__ tokens,
    const float* __restrict__ Wr_f, const float* __restrict__ Wr_b,
    __hip_bfloat16* __restrict__ h_buf)
{
    const int bid  = blockIdx.x;
    const int dir  = bid >> 7;
    const int b    = bid & 127;
    const int tid  = threadIdx.x;
    const int w    = tid >> 6;       // wave 0..7 -> units [16w, 16w+16)
    const int lane = tid & 63;
    const int quad = lane >> 4;
    const int l16  = lane & 15;
    const int unit = 16 * w + l16;   // this lane's unit

    const float* Wr = dir ? Wr_b : Wr_f;

    // B-frags: wb[g][kc]; element j = Wr[kc*32+quad*8+j][g*128 + unit]
    union uf16 { f16x8 v; h2_t p[4]; };
    f16x8 wb[4][4];
    #pragma unroll
    for (int gq = 0; gq < 4; ++gq) {
        const int col = gq * 128 + unit;
        #pragma unroll
        for (int kc = 0; kc < 4; ++kc) {
            const int k0 = kc * 32 + quad * 8;
            uf16 u;
            #pragma unroll
            for (int jj = 0; jj < 4; ++jj)
                u.p[jj] = pk2(Wr[(k0 + 2 * jj)     * G4 + col],
                              Wr[(k0 + 2 * jj + 1) * G4 + col]);
            wb[gq][kc] = u.v;
        }
    }

    // h double-buffer (f16) + xk group double-buffer (bf16 bits)
    __shared__ __align__(16) _Float16 hpl[2][128];
    __shared__ __align__(16) unsigned short xkl[2][GRP][512];  // 16 KB
    if (tid < 128) hpl[0][tid] = (_Float16)0.f;
    float c = 0.f;

    const int tbase = b * T_;
    const long long rowbase = (long long)b * T_;
    // staging gather base: proj[tok][dir*512 + tid]  (tid = gate*128+unit)
    const __hip_bfloat16* prt = proj + dir * 512 + tid;
    const int xw = (tid & 127) * 4 + (tid >> 7);   // LDS slot [unit][gate]

    // prologue: stage group 0 synchronously; preload tokens for group 1
    int tokn[GRP];
    {
        unsigned short v0[GRP];
        #pragma unroll
        for (int d = 0; d < GRP; ++d) {
            int t0 = dir ? (T_ - 1 - d) : d;
            int tk = tokens[tbase + t0];
            v0[d] = *(const unsigned short*)(prt + (long long)tk * 1024);
        }
        #pragma unroll
        for (int d = 0; d < GRP; ++d)
            xkl[0][d][xw] = v0[d];
        #pragma unroll
        for (int d = 0; d < GRP; ++d) {
            int s = GRP + d;
            int t1 = dir ? (T_ - 1 - s) : s;
            tokn[d] = tokens[tbase + t1];
        }
    }
    __syncthreads();

    const int NG = T_ / GRP;   // 64
    for (int g = 0; g < NG; ++g) {
        // issue next group's xk loads (held in regs until group end)
        unsigned short xknx[GRP];
        #pragma unroll
        for (int d = 0; d < GRP; ++d)
            xknx[d] = *(const unsigned short*)(prt + (long long)tokn[d] * 1024);

        // tokens for group g+2 (clamped -> always-valid rows)
        int tokn2[GRP];
        #pragma unroll
        for (int d = 0; d < GRP; ++d) {
            int s = (g + 2) * GRP + d; if (s > T_ - 1) s = T_ - 1;
            int t = dir ? (T_ - 1 - s) : s;
            tokn2[d] = tokens[tbase + t];
        }

        float hreg[GRP];
        #pragma unroll
        for (int d = 0; d < GRP; ++d) {
            // A-frag: broadcast h to all 16 rows (addr depends on quad only)
            f16x8 a[4];
            #pragma unroll
            for (int kc = 0; kc < 4; ++kc)
                a[kc] = *(const f16x8*)&hpl[d & 1][kc * 32 + quad * 8];

            // xk for this step: 8B LDS broadcast read [unit][0..3]
            u16x4 xr = *(const u16x4*)&xkl[g & 1][d][(unsigned)unit * 4];

            f32x4 acc[4];
            #pragma unroll
            for (int gq = 0; gq < 4; ++gq)
                acc[gq] = (f32x4){0.f, 0.f, 0.f, 0.f};
            #pragma unroll
            for (int gq = 0; gq < 4; ++gq)
                #pragma unroll
                for (int kc = 0; kc < 4; ++kc)
                    acc[gq] = __builtin_amdgcn_mfma_f32_16x16x32_f16(
                        a[kc], wb[gq][kc], acc[gq], 0, 0, 0);

            // every lane holds z for its unit in acc[gq][0] (rows identical)
            float zi = acc[0][0] + bf2f(xr.x);
            float zf = acc[1][0] + bf2f(xr.y);
            float zg = acc[2][0] + bf2f(xr.z);
            float zo = acc[3][0] + bf2f(xr.w);
            c = sigmoid_f(zf) * c + sigmoid_f(zi) * tanh_f(zg);
            float h = sigmoid_f(zo) * tanh_f(c);
            hreg[d] = h;

            // publish h for next step (quad 0 writes its 16 units)
            if (quad == 0) hpl[(d + 1) & 1][unit] = (_Float16)h;

            if (d < GRP - 1) {
                // LDS-only barrier: leave vmem in flight (T4)
                asm volatile("s_waitcnt lgkmcnt(0)" ::: "memory");
                __builtin_amdgcn_s_barrier();
                asm volatile("" ::: "memory");   // no load hoisting past barrier
            } else {
                // group boundary: publish next group's xk (compiler inserts
                // the vmcnt wait via data dependence), then barrier
                #pragma unroll
                for (int dd = 0; dd < GRP; ++dd)
                    xkl[(g + 1) & 1][dd][xw] = xknx[dd];
                asm volatile("s_waitcnt lgkmcnt(0)" ::: "memory");
                __builtin_amdgcn_s_barrier();
                asm volatile("" ::: "memory");
            }
        }

        // group end: pack h pairs to bf16 and store (off the serial path)
        unsigned int hp[GRP];
        #pragma unroll
        for (int d = 0; d < GRP; ++d) {
            float hn = __shfl_down(hreg[d], 1, 64);
            hp[d] = ((unsigned int)bf16_bits(hn) << 16) | bf16_bits(hreg[d]);
        }
        if (quad == 0 && !(l16 & 1)) {
            #pragma unroll
            for (int d = 0; d < GRP; ++d) {
                int s = g * GRP + d;
                int t = dir ? (T_ - 1 - s) : s;
                *(unsigned int*)(h_buf + (rowbase + t) * 256 + dir * U_ + unit) =
                    hp[d];
            }
        }

        #pragma unroll
        for (int d = 0; d < GRP; ++d) tokn[d] = tokn2[d];
    }
}

// ---------------------------------------------------------------------------
// Kernel C: em = h_buf(65536x256 bf16) @ ck(256x32) + cb  -> f32 (65536x32).
// ---------------------------------------------------------------------------
__global__ __launch_bounds__(256) void em_kernel(
    const __hip_bfloat16* __restrict__ h_buf,
    const float* __restrict__ ck, const float* __restrict__ cb,
    float* __restrict__ em)
{
    const int tid  = threadIdx.x;
    const int part = tid >> 5;
    const int k    = tid & 31;

    float ckr[32];
    #pragma unroll
    for (int i = 0; i < 32; ++i)
        ckr[i] = ck[(part * 32 + i) * K_ + k];
    const float cbk = cb[k];

    __shared__ float h_l[8][256];
    __shared__ float part_l[8][8][K_];

    const int r0 = blockIdx.x * 64;

    for (int round = 0; round < 8; ++round) {
        const int rbase = r0 + round * 8;
        #pragma unroll
        for (int j = 0; j < 8; ++j)
            h_l[j][tid] = __bfloat162float(h_buf[(long long)(rbase + j) * 256 + tid]);
        __syncthreads();

        #pragma unroll
        for (int j = 0; j < 8; ++j) {
            float pp = 0.f;
            #pragma unroll
            for (int i = 0; i < 32; ++i)
                pp = fmaf(h_l[j][part * 32 + i], ckr[i], pp);
            part_l[j][part][k] = pp;
        }
        __syncthreads();

        {
            int j2 = tid >> 5;
            float e = cbk;
            #pragma unroll
            for (int pq = 0; pq < 8; ++pq) e += part_l[j2][pq][k];
            em[(long long)(rbase + j2) * K_ + k] = e;
        }
        __syncthreads();
    }
}

// ---------------------------------------------------------------------------
// Kernel D: CRF logZ — linear-space chain.
// ---------------------------------------------------------------------------
#define PF_ 8
__global__ __launch_bounds__(64) void crf_kernel(
    const float* __restrict__ em,
    const float* __restrict__ trans,
    float* __restrict__ out)
{
    const int b    = blockIdx.x;
    const int lane = threadIdx.x;
    const int k    = lane & 31;
    const int half = lane >> 5;

    float etr[16];
    #pragma unroll
    for (int i = 0; i < 16; ++i)
        etr[i] = __expf(trans[(half * 16 + i) * K_ + k]);

    const float* em_b = em + (long long)b * T_ * K_;

    float ep[PF_];
    #pragma unroll
    for (int d = 0; d < PF_; ++d)
        ep[d] = em_b[d * K_ + k];

    float w = 0.f;    // linear-space alpha, scaled
    float L = 0.f;    // accumulated log-scale
    for (int tb = 0; tb < T_; tb += PF_) {
        float en[PF_];
        if (tb + PF_ < T_) {
            #pragma unroll
            for (int d = 0; d < PF_; ++d)
                en[d] = em_b[(tb + PF_ + d) * K_ + k];
        } else {
            #pragma unroll
            for (int d = 0; d < PF_; ++d) en[d] = 0.f;
        }

        float eem[PF_];
        #pragma unroll
        for (int d = 0; d < PF_; ++d) eem[d] = __expf(ep[d]);

        #pragma unroll
        for (int d = 0; d < PF_; ++d) {
            if (tb + d == 0) {
                w = eem[d];
            } else {
                float acc = 0.f;
                #pragma unroll
                for (int i = 0; i < 16; ++i) {
                    float wv = __shfl(w, half * 16 + i, 64);
                    acc = fmaf(wv, etr[i], acc);
                }
                acc += __shfl_xor(acc, 32, 64);
                w = acc * eem[d];
            }
        }

        {
            float w0 = __shfl(w, 0, 64);
            w *= rcp_f(w0);
            L += __logf(w0);
        }

        #pragma unroll
        for (int d = 0; d < PF_; ++d) ep[d] = en[d];
    }

    float s = w;
    #pragma unroll
    for (int d = 1; d < 32; d <<= 1)
        s += __shfl_xor(s, d, 64);
    if (lane == 0) out[b] = L + __logf(s);
}

// ---------------------------------------------------------------------------
extern "C" void kernel_launch(void* const* d_in, const int* in_sizes, int n_in,
                              void* d_out, int out_size, void* d_ws, size_t ws_size,
                              hipStream_t stream)
{
    const int*   tokens = (const int*)  d_in[0];
    const float* emb    = (const float*)d_in[1];
    const float* Wk_f   = (const float*)d_in[2];
    const float* Wr_f   = (const float*)d_in[3];
    const float* b_f    = (const float*)d_in[4];
    const float* Wk_b   = (const float*)d_in[5];
    const float* Wr_b   = (const float*)d_in[6];
    const float* b_b    = (const float*)d_in[7];
    const float* ck     = (const float*)d_in[8];
    const float* cb     = (const float*)d_in[9];
    const float* trans  = (const float*)d_in[10];
    float* out = (float*)d_out;

    // ws layout: proj (VP*1024 bf16 = 102.4MB) | h_buf (33.6MB) |
    //            em (8.4MB f32) | Bb (256KB bf16).  Total ~144.7MB.
    const long long ROWS = (long long)B_ * T_;     // 65536
    __hip_bfloat16* proj  = (__hip_bfloat16*)d_ws;
    __hip_bfloat16* h_buf = proj + (long long)VP * 1024;
    float* em = (float*)(h_buf + ROWS * 256);
    __hip_bfloat16* Bb = (__hip_bfloat16*)(em + ROWS * K_);

    hipLaunchKernelGGL(pack_b_kernel, dim3(1024), dim3(128), 0, stream,
                       Wk_f, Wk_b, Bb);
    hipLaunchKernelGGL(proj_mfma_kernel, dim3(VP / 32), dim3(256), 0, stream,
                       emb, Bb, b_f, b_b, proj);
    hipLaunchKernelGGL(lstm_kernel, dim3(256), dim3(512), 0, stream,
                       proj, tokens, Wr_f, Wr_b, h_buf);
    hipLaunchKernelGGL(em_kernel, dim3((int)(ROWS / 64)), dim3(256), 0, stream,
                       h_buf, ck, cb, em);
    hipLaunchKernelGGL(crf_kernel, dim3(B_), dim3(64), 0, stream,
                       em, trans, out);
}